// Round 7
// baseline (11858.392 us; speedup 1.0000x reference)
//
#include <hip/hip_runtime.h>
#include <math.h>

#define TT 512
#define BB 128
#define HH 1024
#define VV 256
#define NTHR 512
#define NBLK 256

typedef __attribute__((ext_vector_type(4)))  int      i32x4;
typedef __attribute__((ext_vector_type(2)))  _Float16 f16x2;
typedef __attribute__((ext_vector_type(8)))  _Float16 f16x8;
typedef __attribute__((ext_vector_type(16))) float    f32x16;

// LDS layout (bytes)
#define ZEX_OFF  0        // [16][32][33] f32 = 67584
#define WXL_OFF  67584    // [256][33] f32 = 33792 (L0 only)
#define PTAB_OFF 101376   // [64 m][2 oct][2 col][8 j] f16 = 4096
#define PEX_OFF  105472   // [8][128][2] f32 = 8192
#define BIAS_OFF 113664   // 32 f32 = 128
#define SMEM_SZ  113792

__device__ __forceinline__ float sigf(float x){ return 1.0f/(1.0f+expf(-x)); }
__device__ __forceinline__ void st16(unsigned short* p, unsigned short v){
  __hip_atomic_store(p, v, __ATOMIC_RELAXED, __HIP_MEMORY_SCOPE_AGENT);
}
__device__ __forceinline__ void stf(float* p, float v){
  __hip_atomic_store(p, v, __ATOMIC_RELAXED, __HIP_MEMORY_SCOPE_AGENT);
}
__device__ __forceinline__ unsigned short h2u(_Float16 h){
  union { _Float16 h; unsigned short u; } c; c.h = h; return c.u;
}

// fp16 pair-dot with f32 accumulate
__device__ __forceinline__ float dot8(f16x8 a, f16x8 b, float c){
  union { f16x8 v; f16x2 p[4]; } ua, ub;
  ua.v = a; ub.v = b;
#if __has_builtin(__builtin_amdgcn_fdot2)
  c = __builtin_amdgcn_fdot2(ua.p[0], ub.p[0], c, false);
  c = __builtin_amdgcn_fdot2(ua.p[1], ub.p[1], c, false);
  c = __builtin_amdgcn_fdot2(ua.p[2], ub.p[2], c, false);
  c = __builtin_amdgcn_fdot2(ua.p[3], ub.p[3], c, false);
#else
  #pragma unroll
  for (int j=0;j<8;++j) c += (float)a[j]*(float)b[j];
#endif
  return c;
}

// device-coherent 16B load (bypasses possibly-stale per-XCD L2)
#define SCLOAD(dst, ptr) asm volatile("global_load_dwordx4 %0, %1, off sc1" : "=v"(dst) : "v"(ptr))
#define WAITG(Q, N) asm volatile("s_waitcnt vmcnt(" #N ")" \
  : "+v"(Q[0]),"+v"(Q[1]),"+v"(Q[2]),"+v"(Q[3]),"+v"(Q[4]),"+v"(Q[5]),"+v"(Q[6]),"+v"(Q[7]))

// contention-free grid barrier: per-block flags, parallel poll, no cache fences
__device__ __forceinline__ void gbar(unsigned* flags, unsigned rnd, int tid, int bid){
  __syncthreads();   // drains vmcnt: this block's sc1 stores are device-visible
  if (tid == 0) __hip_atomic_store(&flags[bid], rnd, __ATOMIC_RELAXED, __HIP_MEMORY_SCOPE_AGENT);
  if (tid < NBLK) {
    int spins = 0;
    while (__hip_atomic_load(&flags[tid], __ATOMIC_RELAXED, __HIP_MEMORY_SCOPE_AGENT) < rnd) {
      __builtin_amdgcn_s_sleep(1);
      if (++spins > (1<<28)) break;   // deadlock insurance
    }
  }
  __syncthreads();
}

// A address: h part (m<64) or L1 K-extension from p0 frags in seq (m>=64)
#define AADDR(M, HB, EB) (((M) < 64) ? ((HB) + (size_t)(M)*1024) : ((EB) + (size_t)((M)-64)*1024))

#define ISSUE_GRP(Q, GI) do{ \
  _Pragma("unroll") \
  for (int kk_=0; kk_<4; ++kk_){ \
    const int m_ = kq*NKW + (GI)*4 + kk_; \
    SCLOAD(Q[kk_],   AADDR(m_, hb0, eb0)); \
    SCLOAD(Q[kk_+4], AADDR(m_, hb1, eb1)); \
  } }while(0)

// consume a group: gate MFMA (if gates on) + p-fold dot2 (if p on, h-slabs only)
#define CONS_GRP(Q, GI) do{ \
  _Pragma("unroll") \
  for (int kk_=0; kk_<4; ++kk_){ \
    const int m_ = kq*NKW + (GI)*4 + kk_; \
    const f16x8 a0_ = __builtin_bit_cast(f16x8, Q[kk_]); \
    const f16x8 a1_ = __builtin_bit_cast(f16x8, Q[kk_+4]); \
    if (gate_on){ \
      acc0 = __builtin_amdgcn_mfma_f32_32x32x16_f16(a0_, breg[(GI)*4+kk_], acc0, 0,0,0); \
      acc1 = __builtin_amdgcn_mfma_f32_32x32x16_f16(a1_, breg[(GI)*4+kk_], acc1, 0,0,0); \
    } \
    if (pf_on && m_ < 64){ \
      const f16x8 t0_ = *(const f16x8*)(smem + PTAB_OFF + (size_t)((m_*2+oct)*2+0)*16); \
      const f16x8 t1_ = *(const f16x8*)(smem + PTAB_OFF + (size_t)((m_*2+oct)*2+1)*16); \
      pacc00 = dot8(a0_, t0_, pacc00); pacc01 = dot8(a0_, t1_, pacc01); \
      pacc10 = dot8(a1_, t0_, pacc10); pacc11 = dot8(a1_, t1_, pacc11); \
    } \
  } }while(0)

// h frag layout (fp16, 256 KB/buffer): element (b,k): byte =
//   (b>>5)*65536 + (k>>4)*1024 + ((b&31) + 32*((k>>3)&1))*16 + (k&7)*2
// p0 K-ext frags live in seq slice t, first 64 KB, same formula with k->v, 16384 strip stride.

template<int LAYER>
__device__ __forceinline__ void pipe_body(
    char* smem, const int* __restrict__ xT,
    const float* __restrict__ Wgx, const float* __restrict__ Wgh,
    const float* __restrict__ Wix, const float* __restrict__ Wih,
    const float* __restrict__ Wfx, const float* __restrict__ Wfh,
    const float* __restrict__ Wox, const float* __restrict__ Woh,
    const float* __restrict__ Wph,
    const float* __restrict__ bg,  const float* __restrict__ bi,
    const float* __restrict__ bf_, const float* __restrict__ bo,
    const float* __restrict__ bp,
    float* __restrict__ seq, char* __restrict__ hA_, char* __restrict__ hB_,
    unsigned* __restrict__ flags)
{
  const int tid = threadIdx.x, bid = blockIdx.x, gb = bid & 127;
  const int wv = tid>>6, lane = tid&63, oct = lane>>5;
  constexpr int NKW = LAYER ? 20 : 16;
  const int rgp = wv>>2, kq = wv&3;
  const int rg0 = rgp*2, rg1 = rgp*2+1;
  const int jb8 = gb*8, pcol0 = gb*2;
  const int u_row = tid & 127, u_hq = tid>>7;
  char* seqc = (char*)seq;

  const float* Wh[4] = { Wgh + (size_t)LAYER*HH*HH, Wih + (size_t)LAYER*HH*HH,
                         Wfh + (size_t)LAYER*HH*HH, Woh + (size_t)LAYER*HH*HH };
  const float* Wx[4] = { Wgx + (size_t)LAYER*VV*HH, Wix + (size_t)LAYER*VV*HH,
                         Wfx + (size_t)LAYER*VV*HH, Wox + (size_t)LAYER*VV*HH };
  const float* bb[4] = { bg + LAYER*HH, bi + LAYER*HH, bf_ + LAYER*HH, bo + LAYER*HH };
  const float* Wph_l = Wph + (size_t)LAYER*HH*VV;
  const float* bp_l  = bp + LAYER*VV;

  float* zex = (float*)(smem + ZEX_OFF);
  float* wxl = (float*)(smem + WXL_OFF);
  float* pex = (float*)(smem + PEX_OFF);
  float* bias_lds = (float*)(smem + BIAS_OFF);

  // ---- stage gate B-frags into registers (once) ----
  f16x8 breg[NKW];
  #pragma unroll
  for (int i=0;i<NKW;++i){
    const int m = kq*NKW + i;
    const int col = lane&31, gg = col>>3, hc = col&7;
    f16x8 v;
    #pragma unroll
    for (int j=0;j<8;++j){
      const int k = m*16 + oct*8 + j;
      const float w = (k < HH) ? Wh[gg][(size_t)k*HH + jb8 + hc]
                               : Wx[gg][(size_t)(k-HH)*HH + jb8 + hc];
      v[j] = (_Float16)w;
    }
    breg[i] = v;
  }
  // ---- stage p-weight table (2 pcols, compact) ----
  for (int idx = tid; idx < 64*2*2; idx += NTHR){
    const int m = idx>>2, oc = (idx>>1)&1, cl = idx&1;
    f16x8 v;
    #pragma unroll
    for (int j=0;j<8;++j){
      const int k = m*16 + oc*8 + j;
      v[j] = (_Float16)Wph_l[(size_t)k*VV + pcol0 + cl];
    }
    *(f16x8*)(smem + PTAB_OFF + (size_t)idx*16) = v;
  }
  // ---- L0: token-gather table ----
  if constexpr (LAYER == 0){
    for (int idx = tid; idx < VV*32; idx += NTHR){
      const int vt = idx>>5, c = idx&31, gg = c>>3, hc = c&7;
      wxl[vt*33 + c] = Wx[gg][(size_t)vt*HH + jb8 + hc];
    }
  }
  if (tid < 32) bias_lds[tid] = bb[tid>>3][jb8 + (tid&7)];

  // zero this layer's t=0 source buffer (hB_)
  {
    float* zb = (float*)hB_;
    for (int idx = gb*NTHR + tid; idx < 65536; idx += 128*NTHR) stf(&zb[idx], 0.f);
  }

  float cst0 = 0.f, cst1 = 0.f;
  unsigned roundNo = 1;
  gbar(flags, roundNo, tid, bid);

  for (int s = 0; s <= TT+2; ++s) {
    const int t = LAYER ? (s-2) : s;
    const bool gate_on = (t >= 0) && (t < TT);
    const bool pf_on   = (t >= 1) && (t <= TT);   // produces p[t-1]
    const bool load_on = gate_on || pf_on;
    const char* hprev = (t&1) ? hA_ : hB_;
    char*       hcur  = (t&1) ? hB_ : hA_;

    f32x16 acc0 = {0,0,0,0,0,0,0,0,0,0,0,0,0,0,0,0};
    f32x16 acc1 = {0,0,0,0,0,0,0,0,0,0,0,0,0,0,0,0};
    float pacc00=0.f, pacc01=0.f, pacc10=0.f, pacc11=0.f;
    int tok = 0;

    if (load_on) {
      const char* hb0 = hprev + (size_t)rg0*65536 + (size_t)lane*16;
      const char* hb1 = hprev + (size_t)rg1*65536 + (size_t)lane*16;
      const char* eb0 = hb0;
      const char* eb1 = hb1;
      if (LAYER == 1 && gate_on){   // K-ext valid only while gates run
        eb0 = seqc + (size_t)t*131072 + (size_t)rg0*16384 + (size_t)lane*16;
        eb1 = seqc + (size_t)t*131072 + (size_t)rg1*16384 + (size_t)lane*16;
      }
      i32x4 qA[8], qB[8];
      if (LAYER == 0 && gate_on)   // oldest in queue: keeps vmcnt counts exact
        asm volatile("global_load_dword %0, %1, off sc1" : "=v"(tok) : "v"(xT + t*BB + u_row));

      ISSUE_GRP(qA, 0);
      ISSUE_GRP(qB, 1);
      WAITG(qA, 8); CONS_GRP(qA, 0); ISSUE_GRP(qA, 2);
      WAITG(qB, 8); CONS_GRP(qB, 1); ISSUE_GRP(qB, 3);
      if constexpr (NKW == 20) {
        WAITG(qA, 8); CONS_GRP(qA, 2); ISSUE_GRP(qA, 4);
        WAITG(qB, 8); CONS_GRP(qB, 3);
        WAITG(qA, 0); CONS_GRP(qA, 4);
      } else {
        WAITG(qA, 8); CONS_GRP(qA, 2);
        WAITG(qB, 0); CONS_GRP(qB, 3);
      }
      if (LAYER == 0 && gate_on) asm volatile("" : "+v"(tok));

      if (gate_on) {   // gate D partials (D: col=lane&31, row=(r&3)+8*(r>>2)+4*oct)
        const int col = lane&31;
        #pragma unroll
        for (int r=0;r<16;++r){
          const int row = (r&3) + 8*(r>>2) + 4*oct;
          zex[(((rg0*4 + kq)*32) + row)*33 + col] = acc0[r];
          zex[(((rg1*4 + kq)*32) + row)*33 + col] = acc1[r];
        }
      }
      if (pf_on) {     // p partials: per-lane rows, 2 cols
        const int r0 = rg0*32 + (lane&31), r1 = rg1*32 + (lane&31);
        pex[((kq*2+oct)*128 + r0)*2 + 0] = pacc00;
        pex[((kq*2+oct)*128 + r0)*2 + 1] = pacc01;
        pex[((kq*2+oct)*128 + r1)*2 + 0] = pacc10;
        pex[((kq*2+oct)*128 + r1)*2 + 1] = pacc11;
      }
    }
    __syncthreads();

    if (gate_on) {
      #pragma unroll
      for (int e=0;e<2;++e){
        const int hc = u_hq*2 + e;
        float z[4];
        #pragma unroll
        for (int g=0; g<4; ++g){
          float sv = bias_lds[g*8 + hc];
          if (LAYER == 0) sv += wxl[tok*33 + g*8 + hc];
          #pragma unroll
          for (int k2=0;k2<4;++k2)
            sv += zex[((((u_row>>5)*4 + k2)*32) + (u_row&31))*33 + g*8 + hc];
          z[g] = sv;
        }
        const float G = tanhf(z[0]), I = sigf(z[1]), F = sigf(z[2]), O = sigf(z[3]);
        float cc = e ? cst1 : cst0;
        cc = fmaf(G, I, cc*F);
        if (e) cst1 = cc; else cst0 = cc;
        const float hv = tanhf(cc)*O;
        const int hid = jb8 + hc;
        const size_t off = (size_t)(u_row>>5)*65536 + (size_t)(hid>>4)*1024
                         + (size_t)((u_row&31) + 32*((hid>>3)&1))*16 + (size_t)(hid&7)*2;
        st16((unsigned short*)(hcur + off), h2u((_Float16)hv));
      }
    }
    if (pf_on && tid < 256) {   // finalize p[t-1] for this block's 2 pcols
      const int row = tid>>1, col = tid&1;
      const int pcol = pcol0 + col;
      float sum = bp_l[pcol];
      #pragma unroll
      for (int i=0;i<8;++i) sum += pex[(i*128 + row)*2 + col];
      if (LAYER == 0) {   // p0 -> fp16 frag region of seq slice t-1 (L1 K-ext)
        const size_t off = (size_t)(t-1)*131072 + (size_t)(row>>5)*16384
                         + (size_t)(pcol>>4)*1024
                         + (size_t)((row&31) + 32*((pcol>>3)&1))*16 + (size_t)(pcol&7)*2;
        st16((unsigned short*)(seqc + off), h2u((_Float16)sum));
      } else {            // p1 -> final fp32 output
        stf(seq + (size_t)(t-1)*BB*VV + (size_t)row*VV + pcol, sum);
      }
    }
    gbar(flags, ++roundNo, tid, bid);
  }
}

__global__ __launch_bounds__(NTHR, 1)
void lstm_pipe(
    const int*   __restrict__ x,
    const float* __restrict__ Wgx, const float* __restrict__ Wgh,
    const float* __restrict__ Wix, const float* __restrict__ Wih,
    const float* __restrict__ Wfx, const float* __restrict__ Wfh,
    const float* __restrict__ Wox, const float* __restrict__ Woh,
    const float* __restrict__ Wph,
    const float* __restrict__ bg,  const float* __restrict__ bi,
    const float* __restrict__ bf_, const float* __restrict__ bo,
    const float* __restrict__ bp,
    float* __restrict__ seq,
    char* __restrict__ hFA, char* __restrict__ hFB,
    char* __restrict__ hGA, char* __restrict__ hGB,
    int* __restrict__ xT, unsigned* __restrict__ flags)
{
  __shared__ char smem[SMEM_SZ];
  const int tid = threadIdx.x, bid = blockIdx.x;

  // transpose x[B][T] -> xT[t][b] once (sc1 stores)
  for (int i = bid*NTHR + tid; i < BB*TT; i += NBLK*NTHR) {
    const int b = i >> 9, t = i & (TT-1);
    __hip_atomic_store(&xT[t*BB + b], x[i], __ATOMIC_RELAXED, __HIP_MEMORY_SCOPE_AGENT);
  }

  if (bid < 128)
    pipe_body<0>(smem, xT, Wgx,Wgh,Wix,Wih,Wfx,Wfh,Wox,Woh,Wph,
                 bg,bi,bf_,bo,bp, seq, hFA, hFB, flags);
  else
    pipe_body<1>(smem, xT, Wgx,Wgh,Wix,Wih,Wfx,Wfh,Wox,Woh,Wph,
                 bg,bi,bf_,bo,bp, seq, hGA, hGB, flags);
}

extern "C" void kernel_launch(void* const* d_in, const int* in_sizes, int n_in,
                              void* d_out, int out_size, void* d_ws, size_t ws_size,
                              hipStream_t stream)
{
  const int*   x   = (const int*)  d_in[0];
  const float* Wgx = (const float*)d_in[1];
  const float* Wgh = (const float*)d_in[2];
  const float* Wix = (const float*)d_in[3];
  const float* Wih = (const float*)d_in[4];
  const float* Wfx = (const float*)d_in[5];
  const float* Wfh = (const float*)d_in[6];
  const float* Wox = (const float*)d_in[7];
  const float* Woh = (const float*)d_in[8];
  const float* Wph = (const float*)d_in[9];
  const float* bg  = (const float*)d_in[10];
  const float* bi  = (const float*)d_in[11];
  const float* bf  = (const float*)d_in[12];
  const float* bo  = (const float*)d_in[13];
  const float* bp  = (const float*)d_in[14];

  float*    seq   = (float*)d_out;
  char*     base  = (char*)d_ws;
  unsigned* flags = (unsigned*)base;                  //   4 KB
  int*      xT    = (int*)(base + 4096);              // 256 KB
  char*     hFA   = base + 4096 + 262144;             // 256 KB (L0 h frags)
  char*     hFB   = hFA + 262144;                     // 256 KB
  char*     hGA   = hFB + 262144;                     // 256 KB (L1 h frags)
  char*     hGB   = hGA + 262144;                     // 256 KB

  hipMemsetAsync(flags, 0, 4096, stream);

  void* args[] = { (void*)&x,
                   (void*)&Wgx, (void*)&Wgh, (void*)&Wix, (void*)&Wih,
                   (void*)&Wfx, (void*)&Wfh, (void*)&Wox, (void*)&Woh,
                   (void*)&Wph,
                   (void*)&bg, (void*)&bi, (void*)&bf, (void*)&bo, (void*)&bp,
                   (void*)&seq, (void*)&hFA, (void*)&hFB, (void*)&hGA, (void*)&hGB,
                   (void*)&xT, (void*)&flags };

  hipLaunchCooperativeKernel((const void*)lstm_pipe, dim3(NBLK), dim3(NTHR),
                             args, 0, stream);
}

// Round 8
// 10282.046 us; speedup vs baseline: 1.1533x; 1.1533x over previous
//
#include <hip/hip_runtime.h>
#include <math.h>

#define TT 512
#define BB 128
#define HH 1024
#define VV 256
#define NTHR 512
#define NBLK 256
#define HSLOT 262144   // bytes per h frag buffer (128 x 1024 fp16)

typedef __attribute__((ext_vector_type(4)))  int      i32x4;
typedef __attribute__((ext_vector_type(2)))  _Float16 f16x2;
typedef __attribute__((ext_vector_type(8)))  _Float16 f16x8;
typedef __attribute__((ext_vector_type(16))) float    f32x16;

// LDS layout (bytes)
#define ZEX_OFF  0        // [16][32][33] f32 = 67584
#define WXL_OFF  67584    // [256][33] f32 = 33792 (L0 only)
#define PTAB_OFF 101376   // [64 m][2 oct][2 col][8 j] f16 = 4096
#define PEX_OFF  105472   // [8][128][2] f32 = 8192
#define BIAS_OFF 113664   // 32 f32 = 128
#define SMEM_SZ  113792

__device__ __forceinline__ float sigf(float x){ return 1.0f/(1.0f+expf(-x)); }
__device__ __forceinline__ void stf(float* p, float v){
  __hip_atomic_store(p, v, __ATOMIC_RELAXED, __HIP_MEMORY_SCOPE_AGENT);
}
__device__ __forceinline__ void st32(unsigned* p, unsigned v){
  __hip_atomic_store(p, v, __ATOMIC_RELAXED, __HIP_MEMORY_SCOPE_AGENT);
}
__device__ __forceinline__ void st64(unsigned long long* p, unsigned long long v){
  __hip_atomic_store(p, v, __ATOMIC_RELAXED, __HIP_MEMORY_SCOPE_AGENT);
}
__device__ __forceinline__ unsigned h2u(_Float16 h){
  union { _Float16 h; unsigned short u; } c; c.h = h; return (unsigned)c.u;
}

// fp16 pair-dot with f32 accumulate
__device__ __forceinline__ float dot8(f16x8 a, f16x8 b, float c){
  union { f16x8 v; f16x2 p[4]; } ua, ub;
  ua.v = a; ub.v = b;
#if __has_builtin(__builtin_amdgcn_fdot2)
  c = __builtin_amdgcn_fdot2(ua.p[0], ub.p[0], c, false);
  c = __builtin_amdgcn_fdot2(ua.p[1], ub.p[1], c, false);
  c = __builtin_amdgcn_fdot2(ua.p[2], ub.p[2], c, false);
  c = __builtin_amdgcn_fdot2(ua.p[3], ub.p[3], c, false);
#else
  #pragma unroll
  for (int j=0;j<8;++j) c += (float)a[j]*(float)b[j];
#endif
  return c;
}

// plain CACHED 16B load — freshness guaranteed by t-windowed addressing + periodic inv
#define CLOAD(dst, ptr) asm volatile("global_load_dwordx4 %0, %1, off" : "=v"(dst) : "v"(ptr))
#define WAITG(Q, N) asm volatile("s_waitcnt vmcnt(" #N ")" \
  : "+v"(Q[0]),"+v"(Q[1]),"+v"(Q[2]),"+v"(Q[3]),"+v"(Q[4]),"+v"(Q[5]),"+v"(Q[6]),"+v"(Q[7]))

// contention-free grid barrier + PERIODIC (not per-step) L1/L2 invalidate.
// All cross-block global writes are sc1 write-through (L3 always current), so
// the acquire fence only discards clean stale lines. Window W=8 slots, inv
// every 4th round => no reader can see a slot's previous-generation lines.
__device__ __forceinline__ void gbar(unsigned* flags, unsigned rnd, int tid, int bid, unsigned invmask){
  __syncthreads();   // drains vmcnt: this block's sc1 stores are device-visible
  if (tid == 0) __hip_atomic_store(&flags[bid], rnd, __ATOMIC_RELAXED, __HIP_MEMORY_SCOPE_AGENT);
  if (tid < NBLK) {
    int spins = 0;
    while (__hip_atomic_load(&flags[tid], __ATOMIC_RELAXED, __HIP_MEMORY_SCOPE_AGENT) < rnd) {
      __builtin_amdgcn_s_sleep(1);
      if (++spins > (1<<28)) break;   // deadlock insurance
    }
  }
  __syncthreads();
  if ((rnd & invmask) == 0) {
    if (tid == 0) __builtin_amdgcn_fence(__ATOMIC_ACQUIRE, "agent");  // buffer_inv
    __syncthreads();
  }
}

// A address: h part (m<64) or L1 K-extension from p0 frags in seq (m>=64)
#define AADDR(M, HB, EB) (((M) < 64) ? ((HB) + (size_t)(M)*1024) : ((EB) + (size_t)((M)-64)*1024))

#define ISSUE_GRP(Q, GI) do{ \
  _Pragma("unroll") \
  for (int kk_=0; kk_<4; ++kk_){ \
    const int m_ = kq*NKW + (GI)*4 + kk_; \
    CLOAD(Q[kk_],   AADDR(m_, hb0, eb0)); \
    CLOAD(Q[kk_+4], AADDR(m_, hb1, eb1)); \
  } }while(0)

// consume a group: gate MFMA (if gates on) + p-fold dot2 (if p on, h-slabs only)
#define CONS_GRP(Q, GI) do{ \
  _Pragma("unroll") \
  for (int kk_=0; kk_<4; ++kk_){ \
    const int m_ = kq*NKW + (GI)*4 + kk_; \
    const f16x8 a0_ = __builtin_bit_cast(f16x8, Q[kk_]); \
    const f16x8 a1_ = __builtin_bit_cast(f16x8, Q[kk_+4]); \
    if (gate_on){ \
      acc0 = __builtin_amdgcn_mfma_f32_32x32x16_f16(a0_, breg[(GI)*4+kk_], acc0, 0,0,0); \
      acc1 = __builtin_amdgcn_mfma_f32_32x32x16_f16(a1_, breg[(GI)*4+kk_], acc1, 0,0,0); \
    } \
    if (pf_on && m_ < 64){ \
      const f16x8 t0_ = *(const f16x8*)(smem + PTAB_OFF + (size_t)((m_*2+oct)*2+0)*16); \
      const f16x8 t1_ = *(const f16x8*)(smem + PTAB_OFF + (size_t)((m_*2+oct)*2+1)*16); \
      pacc00 = dot8(a0_, t0_, pacc00); pacc01 = dot8(a0_, t1_, pacc01); \
      pacc10 = dot8(a1_, t0_, pacc10); pacc11 = dot8(a1_, t1_, pacc11); \
    } \
  } }while(0)

// h frag layout (fp16, 256 KB/slot): element (b,k): byte =
//   (b>>5)*65536 + (k>>4)*1024 + ((b&31) + 32*((k>>3)&1))*16 + (k&7)*2
// p0 K-ext frags live in seq slice t, first 64 KB, same formula with k->v, 16384 strip stride.

template<int LAYER>
__device__ __forceinline__ void pipe_body(
    char* smem, const int* __restrict__ xT,
    const float* __restrict__ Wgx, const float* __restrict__ Wgh,
    const float* __restrict__ Wix, const float* __restrict__ Wih,
    const float* __restrict__ Wfx, const float* __restrict__ Wfh,
    const float* __restrict__ Wox, const float* __restrict__ Woh,
    const float* __restrict__ Wph,
    const float* __restrict__ bg,  const float* __restrict__ bi,
    const float* __restrict__ bf_, const float* __restrict__ bo,
    const float* __restrict__ bp,
    float* __restrict__ seq, char* __restrict__ hWin,
    int wmask, unsigned invmask, unsigned* __restrict__ flags)
{
  const int tid = threadIdx.x, bid = blockIdx.x, gb = bid & 127;
  const int wv = tid>>6, lane = tid&63, oct = lane>>5;
  constexpr int NKW = LAYER ? 20 : 16;
  const int rgp = wv>>2, kq = wv&3;
  const int rg0 = rgp*2, rg1 = rgp*2+1;
  const int jb8 = gb*8, pcol0 = gb*2;
  const int u_row = tid & 127, u_hq = tid>>7;
  char* seqc = (char*)seq;
  char* hbase = hWin + (size_t)LAYER * (wmask+1) * HSLOT;

  const float* Wh[4] = { Wgh + (size_t)LAYER*HH*HH, Wih + (size_t)LAYER*HH*HH,
                         Wfh + (size_t)LAYER*HH*HH, Woh + (size_t)LAYER*HH*HH };
  const float* Wx[4] = { Wgx + (size_t)LAYER*VV*HH, Wix + (size_t)LAYER*VV*HH,
                         Wfx + (size_t)LAYER*VV*HH, Wox + (size_t)LAYER*VV*HH };
  const float* bb[4] = { bg + LAYER*HH, bi + LAYER*HH, bf_ + LAYER*HH, bo + LAYER*HH };
  const float* Wph_l = Wph + (size_t)LAYER*HH*VV;
  const float* bp_l  = bp + LAYER*VV;

  float* zex = (float*)(smem + ZEX_OFF);
  float* wxl = (float*)(smem + WXL_OFF);
  float* pex = (float*)(smem + PEX_OFF);
  float* bias_lds = (float*)(smem + BIAS_OFF);

  // ---- stage gate B-frags into registers (once) ----
  f16x8 breg[NKW];
  #pragma unroll
  for (int i=0;i<NKW;++i){
    const int m = kq*NKW + i;
    const int col = lane&31, gg = col>>3, hc = col&7;
    f16x8 v;
    #pragma unroll
    for (int j=0;j<8;++j){
      const int k = m*16 + oct*8 + j;
      const float w = (k < HH) ? Wh[gg][(size_t)k*HH + jb8 + hc]
                               : Wx[gg][(size_t)(k-HH)*HH + jb8 + hc];
      v[j] = (_Float16)w;
    }
    breg[i] = v;
  }
  // ---- stage p-weight table (2 pcols, compact) ----
  for (int idx = tid; idx < 64*2*2; idx += NTHR){
    const int m = idx>>2, oc = (idx>>1)&1, cl = idx&1;
    f16x8 v;
    #pragma unroll
    for (int j=0;j<8;++j){
      const int k = m*16 + oc*8 + j;
      v[j] = (_Float16)Wph_l[(size_t)k*VV + pcol0 + cl];
    }
    *(f16x8*)(smem + PTAB_OFF + (size_t)idx*16) = v;
  }
  // ---- L0: token-gather table ----
  if constexpr (LAYER == 0){
    for (int idx = tid; idx < VV*32; idx += NTHR){
      const int vt = idx>>5, c = idx&31, gg = c>>3, hc = c&7;
      wxl[vt*33 + c] = Wx[gg][(size_t)vt*HH + jb8 + hc];
    }
  }
  if (tid < 32) bias_lds[tid] = bb[tid>>3][jb8 + (tid&7)];
  const float bp0 = bp_l[pcol0], bp1 = bp_l[pcol0+1];   // preloaded (loop-invariant)

  // zero this layer's t=0 source slot (slot wmask), sc1 write-through
  {
    float* zb = (float*)(hbase + (size_t)wmask*HSLOT);
    for (int idx = gb*NTHR + tid; idx < 65536; idx += 128*NTHR) stf(&zb[idx], 0.f);
  }

  float cst0 = 0.f, cst1 = 0.f;
  unsigned roundNo = 1;
  gbar(flags, roundNo, tid, bid, invmask);

  for (int s = 0; s <= TT+2; ++s) {
    const int t = LAYER ? (s-2) : s;
    const bool gate_on = (t >= 0) && (t < TT);
    const bool pf_on   = (t >= 1) && (t <= TT);   // produces p[t-1]
    const bool load_on = gate_on || pf_on;
    const char* hprev = hbase + (size_t)((t + wmask) & wmask) * HSLOT;
    char*       hcur  = hbase + (size_t)(t & wmask) * HSLOT;

    f32x16 acc0 = {0,0,0,0,0,0,0,0,0,0,0,0,0,0,0,0};
    f32x16 acc1 = {0,0,0,0,0,0,0,0,0,0,0,0,0,0,0,0};
    float pacc00=0.f, pacc01=0.f, pacc10=0.f, pacc11=0.f;
    int tok = 0;

    if (load_on) {
      const char* hb0 = hprev + (size_t)rg0*65536 + (size_t)lane*16;
      const char* hb1 = hprev + (size_t)rg1*65536 + (size_t)lane*16;
      const char* eb0 = hb0;
      const char* eb1 = hb1;
      if (LAYER == 1 && gate_on){   // K-ext valid only while gates run
        eb0 = seqc + (size_t)t*131072 + (size_t)rg0*16384 + (size_t)lane*16;
        eb1 = seqc + (size_t)t*131072 + (size_t)rg1*16384 + (size_t)lane*16;
      }
      i32x4 qA[8], qB[8];
      if (LAYER == 0 && gate_on)   // oldest in queue: keeps vmcnt counts exact
        asm volatile("global_load_dword %0, %1, off" : "=v"(tok) : "v"(xT + t*BB + u_row));

      ISSUE_GRP(qA, 0);
      ISSUE_GRP(qB, 1);
      WAITG(qA, 8); CONS_GRP(qA, 0); ISSUE_GRP(qA, 2);
      WAITG(qB, 8); CONS_GRP(qB, 1); ISSUE_GRP(qB, 3);
      if constexpr (NKW == 20) {
        WAITG(qA, 8); CONS_GRP(qA, 2); ISSUE_GRP(qA, 4);
        WAITG(qB, 8); CONS_GRP(qB, 3);
        WAITG(qA, 0); CONS_GRP(qA, 4);
      } else {
        WAITG(qA, 8); CONS_GRP(qA, 2);
        WAITG(qB, 0); CONS_GRP(qB, 3);
      }
      if (LAYER == 0 && gate_on) asm volatile("" : "+v"(tok));

      if (gate_on) {   // gate D partials (D: col=lane&31, row=(r&3)+8*(r>>2)+4*oct)
        const int col = lane&31;
        #pragma unroll
        for (int r=0;r<16;++r){
          const int row = (r&3) + 8*(r>>2) + 4*oct;
          zex[(((rg0*4 + kq)*32) + row)*33 + col] = acc0[r];
          zex[(((rg1*4 + kq)*32) + row)*33 + col] = acc1[r];
        }
      }
      if (pf_on) {     // p partials: per-lane rows, 2 cols
        const int r0 = rg0*32 + (lane&31), r1 = rg1*32 + (lane&31);
        pex[((kq*2+oct)*128 + r0)*2 + 0] = pacc00;
        pex[((kq*2+oct)*128 + r0)*2 + 1] = pacc01;
        pex[((kq*2+oct)*128 + r1)*2 + 0] = pacc10;
        pex[((kq*2+oct)*128 + r1)*2 + 1] = pacc11;
      }
    }
    __syncthreads();

    if (gate_on) {
      float hvv[2];
      #pragma unroll
      for (int e=0;e<2;++e){
        const int hc = u_hq*2 + e;
        float z[4];
        #pragma unroll
        for (int g=0; g<4; ++g){
          float sv = bias_lds[g*8 + hc];
          if (LAYER == 0) sv += wxl[tok*33 + g*8 + hc];
          #pragma unroll
          for (int k2=0;k2<4;++k2)
            sv += zex[((((u_row>>5)*4 + k2)*32) + (u_row&31))*33 + g*8 + hc];
          z[g] = sv;
        }
        const float G = tanhf(z[0]), I = sigf(z[1]), F = sigf(z[2]), O = sigf(z[3]);
        float cc = e ? cst1 : cst0;
        cc = fmaf(G, I, cc*F);
        if (e) cst1 = cc; else cst0 = cc;
        hvv[e] = tanhf(cc)*O;
      }
      // packed 4B store of the two adjacent h columns (hid0 even)
      const int hid0 = jb8 + u_hq*2;
      const size_t off = (size_t)(u_row>>5)*65536 + (size_t)(hid0>>4)*1024
                       + (size_t)((u_row&31) + 32*((hid0>>3)&1))*16 + (size_t)(hid0&7)*2;
      st32((unsigned*)(hcur + off), h2u((_Float16)hvv[0]) | (h2u((_Float16)hvv[1])<<16));
    }
    if (pf_on && tid < 128) {   // finalize p[t-1] for this block's 2 pcols
      const int row = tid;
      float sum0 = bp0, sum1 = bp1;
      #pragma unroll
      for (int i=0;i<8;++i){
        sum0 += pex[(i*128 + row)*2 + 0];
        sum1 += pex[(i*128 + row)*2 + 1];
      }
      if (LAYER == 0) {   // p0 -> fp16 frag region of seq slice t-1 (L1 K-ext), packed 4B
        const size_t off = (size_t)(t-1)*131072 + (size_t)(row>>5)*16384
                         + (size_t)(pcol0>>4)*1024
                         + (size_t)((row&31) + 32*((pcol0>>3)&1))*16 + (size_t)(pcol0&7)*2;
        st32((unsigned*)(seqc + off), h2u((_Float16)sum0) | (h2u((_Float16)sum1)<<16));
      } else {            // p1 -> final fp32 output, packed 8B
        union { float f[2]; unsigned long long u; } pk;
        pk.f[0] = sum0; pk.f[1] = sum1;
        st64((unsigned long long*)(seq + (size_t)(t-1)*BB*VV + (size_t)row*VV + pcol0), pk.u);
      }
    }
    gbar(flags, ++roundNo, tid, bid, invmask);
  }
}

__global__ __launch_bounds__(NTHR, 1)
void lstm_pipe(
    const int*   __restrict__ x,
    const float* __restrict__ Wgx, const float* __restrict__ Wgh,
    const float* __restrict__ Wix, const float* __restrict__ Wih,
    const float* __restrict__ Wfx, const float* __restrict__ Wfh,
    const float* __restrict__ Wox, const float* __restrict__ Woh,
    const float* __restrict__ Wph,
    const float* __restrict__ bg,  const float* __restrict__ bi,
    const float* __restrict__ bf_, const float* __restrict__ bo,
    const float* __restrict__ bp,
    float* __restrict__ seq, char* __restrict__ hWin,
    int wmask, unsigned invmask,
    int* __restrict__ xT, unsigned* __restrict__ flags)
{
  __shared__ char smem[SMEM_SZ];
  const int tid = threadIdx.x, bid = blockIdx.x;

  // transpose x[B][T] -> xT[t][b] once (sc1 stores; readers cold-fill => fresh)
  for (int i = bid*NTHR + tid; i < BB*TT; i += NBLK*NTHR) {
    const int b = i >> 9, t = i & (TT-1);
    __hip_atomic_store(&xT[t*BB + b], x[i], __ATOMIC_RELAXED, __HIP_MEMORY_SCOPE_AGENT);
  }

  if (bid < 128)
    pipe_body<0>(smem, xT, Wgx,Wgh,Wix,Wih,Wfx,Wfh,Wox,Woh,Wph,
                 bg,bi,bf_,bo,bp, seq, hWin, wmask, invmask, flags);
  else
    pipe_body<1>(smem, xT, Wgx,Wgh,Wix,Wih,Wfx,Wfh,Wox,Woh,Wph,
                 bg,bi,bf_,bo,bp, seq, hWin, wmask, invmask, flags);
}

extern "C" void kernel_launch(void* const* d_in, const int* in_sizes, int n_in,
                              void* d_out, int out_size, void* d_ws, size_t ws_size,
                              hipStream_t stream)
{
  const int*   x   = (const int*)  d_in[0];
  const float* Wgx = (const float*)d_in[1];
  const float* Wgh = (const float*)d_in[2];
  const float* Wix = (const float*)d_in[3];
  const float* Wih = (const float*)d_in[4];
  const float* Wfx = (const float*)d_in[5];
  const float* Wfh = (const float*)d_in[6];
  const float* Wox = (const float*)d_in[7];
  const float* Woh = (const float*)d_in[8];
  const float* Wph = (const float*)d_in[9];
  const float* bg  = (const float*)d_in[10];
  const float* bi  = (const float*)d_in[11];
  const float* bf  = (const float*)d_in[12];
  const float* bo  = (const float*)d_in[13];
  const float* bp  = (const float*)d_in[14];

  float*    seq   = (float*)d_out;
  char*     base  = (char*)d_ws;
  unsigned* flags = (unsigned*)base;                  //   4 KB
  int*      xT    = (int*)(base + 4096);              // 256 KB
  char*     hWin  = base + 4096 + 262144;             // 2 layers x W x 256 KB

  // window size: prefer W=8 (inv every 4 steps); fall back to W=4 if ws is tight
  const size_t fixed = 4096 + 262144;
  int W = (ws_size >= fixed + (size_t)16*HSLOT) ? 8 : 4;
  int wmask = W - 1;
  unsigned invmask = (unsigned)(W/2 - 1);

  hipMemsetAsync(flags, 0, 4096, stream);

  void* args[] = { (void*)&x,
                   (void*)&Wgx, (void*)&Wgh, (void*)&Wix, (void*)&Wih,
                   (void*)&Wfx, (void*)&Wfh, (void*)&Wox, (void*)&Woh,
                   (void*)&Wph,
                   (void*)&bg, (void*)&bi, (void*)&bf, (void*)&bo, (void*)&bp,
                   (void*)&seq, (void*)&hWin, (void*)&wmask, (void*)&invmask,
                   (void*)&xT, (void*)&flags };

  hipLaunchCooperativeKernel((const void*)lstm_pipe, dim3(NBLK), dim3(NTHR),
                             args, 0, stream);
}